// Round 6
// baseline (145.768 us; speedup 1.0000x reference)
//
#include <hip/hip_runtime.h>

typedef unsigned short u16;
typedef unsigned int u32;
typedef __bf16 bf16;
typedef __bf16 bf16x8 __attribute__((ext_vector_type(8)));
typedef float f32x4 __attribute__((ext_vector_type(4)));
typedef u32 u32x2 __attribute__((ext_vector_type(2)));
typedef u32 u32x4 __attribute__((ext_vector_type(4)));

// Problem: B=4, S=2048, DIM=1024, DK=DV=128, rows = B*S = 8192.
// One persistent megakernel: 256 blocks (1/CU, forced by 128 KB LDS) x 512 thr.
// Phases: [wprep] gridbar [qkv gemm] gridbar [attn + in-block combine -> out].

__device__ __forceinline__ void gl_lds16(const void* g, void* l) {
  __builtin_amdgcn_global_load_lds(
      (const __attribute__((address_space(1))) void*)g,
      (__attribute__((address_space(3))) void*)l, 16, 0, 0);
}
__device__ __forceinline__ u16 bfbits(float f) {
  return __builtin_bit_cast(u16, (bf16)f);
}
__device__ __forceinline__ u32 pk2(float lo, float hi) {
  return (u32)bfbits(lo) | ((u32)bfbits(hi) << 16);
}

union LDSU {
  struct { u16 st[2][64 * 68]; } wp;                              // 17.4 KB
  struct { float sx[2][2][64 * 64]; u16 sw[2][2][128 * 64]; } qk; // 128 KB
  struct { u16 sk[4][64 * 128]; u16 sv[4][128 * 64]; } at;        // 128 KB
  struct { float oc[4][32 * 132]; float ml[4][2][32]; } cb;       // 68.6 KB
};

// Device-scope grid barrier. bar[0]=arrive, bar[1]=release; zeroed per launch.
__device__ __forceinline__ void gridbar(u32* bar, u32 nblk) {
  __syncthreads();
  if (threadIdx.x == 0) {
    __threadfence();
    u32 old = __hip_atomic_fetch_add(&bar[0], 1u, __ATOMIC_ACQ_REL,
                                     __HIP_MEMORY_SCOPE_AGENT);
    if (old == nblk - 1) {
      __hip_atomic_store(&bar[1], 1u, __ATOMIC_RELEASE, __HIP_MEMORY_SCOPE_AGENT);
    } else {
      while (__hip_atomic_load(&bar[1], __ATOMIC_ACQUIRE,
                               __HIP_MEMORY_SCOPE_AGENT) == 0u)
        __builtin_amdgcn_s_sleep(2);
    }
  }
  __syncthreads();
}

__global__ __launch_bounds__(512, 2) void mega_kernel(
    const float* __restrict__ x,
    const float* __restrict__ Wq, const float* __restrict__ bq,
    const float* __restrict__ Wk, const float* __restrict__ bk,
    const float* __restrict__ Wv, const float* __restrict__ bv,
    u16* __restrict__ qb, u16* __restrict__ kb, u16* __restrict__ vt,
    u16* __restrict__ Wt, u32* __restrict__ bars, float* __restrict__ out)
{
  __shared__ __attribute__((aligned(16))) LDSU lds;
  const int tid = threadIdx.x;

  // ---------------- Phase 0: W transpose+convert (96 tiles, 2 engines) ------
  if (blockIdx.x < 48) {
    const int e = tid >> 8, etid = tid & 255;
    const int tile = blockIdx.x * 2 + e;
    const int m = tile >> 5, rem = tile & 31, kt = rem >> 1, nt = rem & 1;
    const float* W = (m == 0) ? Wq : (m == 1) ? Wk : Wv;
    const int k0 = kt * 64, n0 = nt * 64;
    u16* st = lds.wp.st[e];
#pragma unroll
    for (int i = 0; i < 4; ++i) {
      int kk = i * 16 + (etid >> 4), nn = (etid & 15) * 4;
      f32x4 w = *(const f32x4*)&W[(size_t)(k0 + kk) * 128 + n0 + nn];
      st[kk * 68 + nn]     = bfbits(w[0]); st[kk * 68 + nn + 1] = bfbits(w[1]);
      st[kk * 68 + nn + 2] = bfbits(w[2]); st[kk * 68 + nn + 3] = bfbits(w[3]);
    }
    __syncthreads();
#pragma unroll
    for (int i = 0; i < 4; ++i) {
      int nn = i * 16 + (etid >> 4), kk = (etid & 15) * 4;
      ushort4 u;
      u.x = st[kk * 68 + nn]; u.y = st[(kk + 1) * 68 + nn];
      u.z = st[(kk + 2) * 68 + nn]; u.w = st[(kk + 3) * 68 + nn];
      *(ushort4*)&Wt[(size_t)m * 131072 + (size_t)(n0 + nn) * 1024 + k0 + kk] = u;
    }
  }
  gridbar(bars, 256);

  // ---------------- Phase 1: QKV GEMM (384 tiles 64x128, 2 engines) ---------
  if (blockIdx.x < 192) {
    const int e = tid >> 8, etid = tid & 255;
    const int wid = etid >> 6, lane = etid & 63;
    const int vtile = blockIdx.x * 2 + e;
    const int m = vtile >> 7;
    const int row0 = (vtile & 127) * 64;
    const u16* W = Wt + (size_t)m * 131072;
    const int wr = wid >> 1, wc = wid & 1;

    auto STAGE = [&](int buf, int k0) {
#pragma unroll
      for (int i = 0; i < 4; ++i) {  // x-tile: 64 rows x 16 chunks of 16B
        int fc = i * 256 + etid; int r = fc >> 4, c = fc & 15;
        gl_lds16(x + (size_t)(row0 + r) * 1024 + k0 + ((c ^ (r & 15)) << 2),
                 (char*)&lds.qk.sx[e][buf][0] + fc * 16);
      }
#pragma unroll
      for (int i = 0; i < 4; ++i) {  // W-tile: 128 rows x 8 chunks of 16B
        int fc = i * 256 + etid; int r = fc >> 3, c = fc & 7;
        gl_lds16(W + (size_t)r * 1024 + k0 + ((c ^ (r & 7)) << 3),
                 (char*)&lds.qk.sw[e][buf][0] + fc * 16);
      }
    };

    f32x4 acc[2][4] = {};
    STAGE(0, 0);
    asm volatile("s_waitcnt vmcnt(0)" ::: "memory");
    __syncthreads();
    int cur = 0;

    for (int kt = 0; kt < 16; ++kt) {
      if (kt < 15) STAGE(cur ^ 1, (kt + 1) * 64);
      const float* sxc = &lds.qk.sx[e][cur][0];
      const u16*   swc = &lds.qk.sw[e][cur][0];
#pragma unroll
      for (int ks = 0; ks < 2; ++ks) {
        bf16x8 af[2], bfr[4];
#pragma unroll
        for (int mr = 0; mr < 2; ++mr) {
          int row = wr * 32 + mr * 16 + (lane & 15);
          int c0 = ks * 8 + (lane >> 4) * 2;
          f32x4 lo = *(const f32x4*)(sxc + row * 64 + ((c0 ^ (row & 15)) << 2));
          f32x4 hi = *(const f32x4*)(sxc + row * 64 + (((c0 + 1) ^ (row & 15)) << 2));
          bf16x8 v;
          v[0] = (bf16)lo[0]; v[1] = (bf16)lo[1]; v[2] = (bf16)lo[2]; v[3] = (bf16)lo[3];
          v[4] = (bf16)hi[0]; v[5] = (bf16)hi[1]; v[6] = (bf16)hi[2]; v[7] = (bf16)hi[3];
          af[mr] = v;
        }
#pragma unroll
        for (int nr = 0; nr < 4; ++nr) {
          int row = wc * 64 + nr * 16 + (lane & 15);
          int ch = (ks * 4 + (lane >> 4)) ^ (row & 7);
          bfr[nr] = *(const bf16x8*)(swc + row * 64 + ch * 8);
        }
#pragma unroll
        for (int mr = 0; mr < 2; ++mr)
#pragma unroll
          for (int nr = 0; nr < 4; ++nr)
            acc[mr][nr] = __builtin_amdgcn_mfma_f32_16x16x32_bf16(af[mr], bfr[nr], acc[mr][nr], 0, 0, 0);
      }
      if (kt < 15) {
        asm volatile("s_waitcnt vmcnt(0)" ::: "memory");
        __syncthreads();
        cur ^= 1;
      }
    }

    const float* bias = (m == 0) ? bq : (m == 1) ? bk : bv;
    u16* qk = (m == 0) ? qb : kb;
#pragma unroll
    for (int mr = 0; mr < 2; ++mr) {
#pragma unroll
      for (int nr = 0; nr < 4; ++nr) {
        int col = wc * 64 + nr * 16 + (lane & 15);
        float bc = bias[col];
        int grow = row0 + wr * 32 + mr * 16 + (lane >> 4) * 4;
        if (m == 2) {
          int bb = grow >> 11, s = grow & 2047;
          ushort4 u;
          u.x = bfbits(acc[mr][nr][0] + bc);
          u.y = bfbits(acc[mr][nr][1] + bc);
          u.z = bfbits(acc[mr][nr][2] + bc);
          u.w = bfbits(acc[mr][nr][3] + bc);
          *(ushort4*)&vt[(size_t)bb * 262144 + (size_t)col * 2048 + s] = u;
        } else {
#pragma unroll
          for (int r = 0; r < 4; ++r)
            qk[(size_t)(grow + r) * 128 + col] = bfbits(acc[mr][nr][r] + bc);
        }
      }
    }
  }
  gridbar(bars + 32, 256);

  // ---------------- Phase 2: attention, 4 split-engines + in-block combine --
  {
    const int e2 = tid >> 7;           // engine = KV split 0..3 (2 waves each)
    const int ew = (tid >> 6) & 1;     // wave within engine
    const int etid = tid & 127;
    const int lane = tid & 63, g = lane >> 4;
    const int qt5 = blockIdx.x >> 2, b = blockIdx.x & 3;
    const int qrow = qt5 * 32 + ew * 16;
    const size_t qg = (size_t)b * 2048 + qrow;
    const u16* kbase = kb + ((size_t)b * 2048 + e2 * 512) * 128;
    const u16* vbase = vt + (size_t)b * 262144 + e2 * 512;
    u16* skc = lds.at.sk[e2];
    u16* svc = lds.at.sv[e2];

    bf16x8 qf[4];
#pragma unroll
    for (int kg = 0; kg < 4; ++kg)
      qf[kg] = *(const bf16x8*)&qb[(qg + (lane & 15)) * 128 + kg * 32 + g * 8];

    float m_run = -INFINITY, l_run = 0.f;
    f32x4 acc_o[8] = {};
    const float scale = 0.08838834764831845f;   // 128^-0.5

    for (int t = 0; t < 8; ++t) {
      // serial stage (single-buffered; 2 waves cover 1024+1024 chunks)
#pragma unroll
      for (int i = 0; i < 8; ++i) {  // K-tile: 64 rows x 16 chunks
        int fc = i * 128 + etid; int r = fc >> 4, c = fc & 15;
        gl_lds16(kbase + (size_t)(t * 64 + r) * 128 + ((c ^ (r & 7)) << 3),
                 (char*)skc + fc * 16);
      }
#pragma unroll
      for (int i = 0; i < 8; ++i) {  // V^T-tile: 128 rows x 8 chunks
        int fc = i * 128 + etid; int r = fc >> 3, c = fc & 7;
        gl_lds16(vbase + (size_t)r * 2048 + t * 64 + ((c ^ (r & 7)) << 3),
                 (char*)svc + fc * 16);
      }
      asm volatile("s_waitcnt vmcnt(0)" ::: "memory");
      __syncthreads();

      // S^T[j][q]: lane holds q = lane&15, j = jg*16 + g*4 + r
      f32x4 sT[4] = {};
#pragma unroll
      for (int kg = 0; kg < 4; ++kg)
#pragma unroll
        for (int jg = 0; jg < 4; ++jg) {
          int row = jg * 16 + (lane & 15);
          int ch = (kg * 4 + g) ^ (row & 7);
          bf16x8 kf = *(const bf16x8*)(skc + row * 128 + ch * 8);
          sT[jg] = __builtin_amdgcn_mfma_f32_16x16x32_bf16(kf, qf[kg], sT[jg], 0, 0, 0);
        }

      // lane-local online softmax
      float mx = fmaxf(fmaxf(fmaxf(sT[0][0], sT[0][1]), fmaxf(sT[0][2], sT[0][3])),
                       fmaxf(fmaxf(sT[1][0], sT[1][1]), fmaxf(sT[1][2], sT[1][3])));
      mx = fmaxf(mx, fmaxf(fmaxf(fmaxf(sT[2][0], sT[2][1]), fmaxf(sT[2][2], sT[2][3])),
                           fmaxf(fmaxf(sT[3][0], sT[3][1]), fmaxf(sT[3][2], sT[3][3]))));
      mx = fmaxf(mx, __shfl_xor(mx, 16));
      mx = fmaxf(mx, __shfl_xor(mx, 32));
      float mn = fmaxf(m_run, mx * scale);

      float rs = 0.f;
      u32 Wp[4][2];
#pragma unroll
      for (int jg = 0; jg < 4; ++jg) {
        float e0 = __expf(fmaf(sT[jg][0], scale, -mn));
        float e1 = __expf(fmaf(sT[jg][1], scale, -mn));
        float e2v = __expf(fmaf(sT[jg][2], scale, -mn));
        float e3 = __expf(fmaf(sT[jg][3], scale, -mn));
        rs += (e0 + e1) + (e2v + e3);
        Wp[jg][0] = pk2(e0, e1);
        Wp[jg][1] = pk2(e2v, e3);
      }
      rs += __shfl_xor(rs, 16);
      rs += __shfl_xor(rs, 32);
      float a = __expf(m_run - mn);
      l_run = l_run * a + rs;
      m_run = mn;
#pragma unroll
      for (int dg = 0; dg < 8; ++dg) acc_o[dg] *= a;

      bf16x8 pfr[2];
#pragma unroll
      for (int k2 = 0; k2 < 2; ++k2) {
        u32x4 wv = {Wp[2 * k2][0], Wp[2 * k2][1], Wp[2 * k2 + 1][0], Wp[2 * k2 + 1][1]};
        pfr[k2] = __builtin_bit_cast(bf16x8, wv);
      }

      const int vb = 4 * (g & 1);
#pragma unroll
      for (int dg = 0; dg < 8; ++dg) {
        int row = dg * 16 + (lane & 15);
#pragma unroll
        for (int k2 = 0; k2 < 2; ++k2) {
          int c0 = (4 * k2 + (g >> 1)) ^ (row & 7);
          int c1 = (4 * k2 + 2 + (g >> 1)) ^ (row & 7);
          u32x2 lo = *(const u32x2*)(svc + row * 64 + c0 * 8 + vb);
          u32x2 hi = *(const u32x2*)(svc + row * 64 + c1 * 8 + vb);
          u32x4 w4 = {lo[0], lo[1], hi[0], hi[1]};
          bf16x8 vf = __builtin_bit_cast(bf16x8, w4);
          acc_o[dg] = __builtin_amdgcn_mfma_f32_16x16x32_bf16(vf, pfr[k2], acc_o[dg], 0, 0, 0);
        }
      }
      __syncthreads();   // tiles consumed; safe to re-stage / reuse LDS
    }

    // in-block combine of the 4 split partials via LDS
    int q32 = ew * 16 + (lane & 15);
    float* oc = lds.cb.oc[e2];
#pragma unroll
    for (int dg = 0; dg < 8; ++dg)
      *(f32x4*)&oc[q32 * 132 + dg * 16 + g * 4] = acc_o[dg];
    if (g == 0) {
      lds.cb.ml[e2][0][q32] = m_run;
      lds.cb.ml[e2][1][q32] = l_run;
    }
    __syncthreads();

    int q = tid >> 4, dq = tid & 15;
    float m0 = lds.cb.ml[0][0][q], m1 = lds.cb.ml[1][0][q];
    float m2 = lds.cb.ml[2][0][q], m3 = lds.cb.ml[3][0][q];
    float ms = fmaxf(fmaxf(m0, m1), fmaxf(m2, m3));
    float w0 = __expf(m0 - ms), w1 = __expf(m1 - ms);
    float w2 = __expf(m2 - ms), w3 = __expf(m3 - ms);
    float den = w0 * lds.cb.ml[0][1][q] + w1 * lds.cb.ml[1][1][q]
              + w2 * lds.cb.ml[2][1][q] + w3 * lds.cb.ml[3][1][q];
    float inv = 1.0f / den;
#pragma unroll
    for (int h = 0; h < 2; ++h) {
      int d = dq * 8 + h * 4;
      f32x4 a0 = *(const f32x4*)&lds.cb.oc[0][q * 132 + d];
      f32x4 a1 = *(const f32x4*)&lds.cb.oc[1][q * 132 + d];
      f32x4 a2 = *(const f32x4*)&lds.cb.oc[2][q * 132 + d];
      f32x4 a3 = *(const f32x4*)&lds.cb.oc[3][q * 132 + d];
      f32x4 r = (a0 * w0 + a1 * w1 + a2 * w2 + a3 * w3) * inv;
      *(f32x4*)&out[((size_t)b * 2048 + qt5 * 32 + q) * 128 + d] = r;
    }
  }
}

// ---------------- launch ----------------------------------------------------
// Workspace: 0 qb (2MB) | 2MB kb (2MB) | 4MB vt (2MB) | 6MB Wt (0.75MB)
//            7MB barrier state (256 B, zeroed each launch)
extern "C" void kernel_launch(void* const* d_in, const int* in_sizes, int n_in,
                              void* d_out, int out_size, void* d_ws, size_t ws_size,
                              hipStream_t stream)
{
  (void)in_sizes; (void)n_in; (void)out_size; (void)ws_size;
  const float* x  = (const float*)d_in[0];
  const float* Wq = (const float*)d_in[1];
  const float* bq = (const float*)d_in[2];
  const float* Wk = (const float*)d_in[3];
  const float* bk = (const float*)d_in[4];
  const float* Wv = (const float*)d_in[5];
  const float* bv = (const float*)d_in[6];
  char* ws = (char*)d_ws;
  u16* qbuf  = (u16*)(ws);
  u16* kbuf  = (u16*)(ws + (2u << 20));
  u16* vtbuf = (u16*)(ws + (4u << 20));
  u16* Wt    = (u16*)(ws + (6u << 20));
  u32* bars  = (u32*)(ws + (7u << 20));

  hipMemsetAsync((void*)bars, 0, 256, stream);
  mega_kernel<<<256, 512, 0, stream>>>(x, Wq, bq, Wk, bk, Wv, bv,
                                       qbuf, kbuf, vtbuf, Wt, bars, (float*)d_out);
}

// Round 7
// 61.704 us; speedup vs baseline: 2.3624x; 2.3624x over previous
//
#include <hip/hip_runtime.h>

typedef unsigned short u16;
typedef unsigned int u32;
typedef __bf16 bf16;
typedef __bf16 bf16x8 __attribute__((ext_vector_type(8)));
typedef float f32x4 __attribute__((ext_vector_type(4)));
typedef u32 u32x4 __attribute__((ext_vector_type(4)));

// Problem constants: B=4, S=2048, DIM=1024, DK=DV=128, rows = B*S = 8192.

__device__ __forceinline__ void gl_lds16(const void* g, void* l) {
  __builtin_amdgcn_global_load_lds(
      (const __attribute__((address_space(1))) void*)g,
      (__attribute__((address_space(3))) void*)l, 16, 0, 0);
}
__device__ __forceinline__ u16 bfbits(float f) {
  return __builtin_bit_cast(u16, (bf16)f);
}
__device__ __forceinline__ u32 pk2(float lo, float hi) {
  return (u32)bfbits(lo) | ((u32)bfbits(hi) << 16);
}

// ---------------- W transpose + convert: Wt[m][n][k] = bf16(W_m[k][n]) -------
__global__ __launch_bounds__(256) void wprep_kernel(
    const float* __restrict__ Wq, const float* __restrict__ Wk,
    const float* __restrict__ Wv, u16* __restrict__ Wt) {
  __shared__ u16 st[64][72];   // pad 72: transpose-read stride 576B -> 2-way (free)
  const int tid = threadIdx.x;
  const int m = blockIdx.x >> 5, rem = blockIdx.x & 31, kt = rem >> 1, nt = rem & 1;
  const float* W = (m == 0) ? Wq : (m == 1) ? Wk : Wv;
  const int k0 = kt * 64, n0 = nt * 64;
#pragma unroll
  for (int i = 0; i < 4; ++i) {
    int kk = i * 16 + (tid >> 4), nn = (tid & 15) * 4;
    f32x4 w = *(const f32x4*)&W[(size_t)(k0 + kk) * 128 + n0 + nn];
    st[kk][nn]     = bfbits(w[0]); st[kk][nn + 1] = bfbits(w[1]);
    st[kk][nn + 2] = bfbits(w[2]); st[kk][nn + 3] = bfbits(w[3]);
  }
  __syncthreads();
#pragma unroll
  for (int i = 0; i < 4; ++i) {
    int nn = i * 16 + (tid >> 4), kk = (tid & 15) * 4;
    ushort4 u;
    u.x = st[kk][nn]; u.y = st[kk + 1][nn]; u.z = st[kk + 2][nn]; u.w = st[kk + 3][nn];
    *(ushort4*)&Wt[(size_t)m * 131072 + (size_t)(n0 + nn) * 1024 + k0 + kk] = u;
  }
}

// ---------------- QKV projection GEMM --------------------------------------
// Unchanged engine; only the V store now permutes columns within each
// 32-s block: s' = (s&~31) | (g*8 + mr*4 + rr)  [s = 16*mr + 4*g + rr]
// so attn's PV A-fragment is a single contiguous b128.
__global__ __launch_bounds__(256) void qkv_gemm(
    const float* __restrict__ x, const u16* __restrict__ Wt,
    const float* __restrict__ bq, const float* __restrict__ bk, const float* __restrict__ bv,
    u16* __restrict__ qb, u16* __restrict__ kb, u16* __restrict__ vt)
{
  __shared__ __attribute__((aligned(16))) float sx[2][64 * 64];
  __shared__ __attribute__((aligned(16))) u16   sw[2][128 * 64];
  const int tid = threadIdx.x, wid = tid >> 6, lane = tid & 63;
  const int m = blockIdx.y;
  const int row0 = blockIdx.x * 64;
  const u16* W = Wt + (size_t)m * 131072;
  const int wr = wid >> 1, wc = wid & 1;

  auto STAGE = [&](int buf, int k0) {
#pragma unroll
    for (int i = 0; i < 4; ++i) {
      int fc = i * 256 + tid; int r = fc >> 4, c = fc & 15;
      gl_lds16(x + (size_t)(row0 + r) * 1024 + k0 + ((c ^ (r & 15)) << 2),
               (char*)&sx[buf][0] + fc * 16);
    }
#pragma unroll
    for (int i = 0; i < 4; ++i) {
      int fc = i * 256 + tid; int r = fc >> 3, c = fc & 7;
      gl_lds16(W + (size_t)r * 1024 + k0 + ((c ^ (r & 7)) << 3),
               (char*)&sw[buf][0] + fc * 16);
    }
  };

  f32x4 acc[2][4] = {};
  STAGE(0, 0);
  asm volatile("s_waitcnt vmcnt(0)" ::: "memory");
  __syncthreads();
  int cur = 0;

  for (int kt = 0; kt < 16; ++kt) {
    if (kt < 15) STAGE(cur ^ 1, (kt + 1) * 64);
    const float* sxc = &sx[cur][0];
    const u16*   swc = &sw[cur][0];
#pragma unroll
    for (int ks = 0; ks < 2; ++ks) {
      bf16x8 af[2], bfr[4];
#pragma unroll
      for (int mr = 0; mr < 2; ++mr) {
        int row = wr * 32 + mr * 16 + (lane & 15);
        int c0 = ks * 8 + (lane >> 4) * 2;
        f32x4 lo = *(const f32x4*)(sxc + row * 64 + ((c0 ^ (row & 15)) << 2));
        f32x4 hi = *(const f32x4*)(sxc + row * 64 + (((c0 + 1) ^ (row & 15)) << 2));
        bf16x8 v;
        v[0] = (bf16)lo[0]; v[1] = (bf16)lo[1]; v[2] = (bf16)lo[2]; v[3] = (bf16)lo[3];
        v[4] = (bf16)hi[0]; v[5] = (bf16)hi[1]; v[6] = (bf16)hi[2]; v[7] = (bf16)hi[3];
        af[mr] = v;
      }
#pragma unroll
      for (int nr = 0; nr < 4; ++nr) {
        int row = wc * 64 + nr * 16 + (lane & 15);
        int ch = (ks * 4 + (lane >> 4)) ^ (row & 7);
        bfr[nr] = *(const bf16x8*)(swc + row * 64 + ch * 8);
      }
#pragma unroll
      for (int mr = 0; mr < 2; ++mr)
#pragma unroll
        for (int nr = 0; nr < 4; ++nr)
          acc[mr][nr] = __builtin_amdgcn_mfma_f32_16x16x32_bf16(af[mr], bfr[nr], acc[mr][nr], 0, 0, 0);
    }
    if (kt < 15) {
      asm volatile("s_waitcnt vmcnt(0)" ::: "memory");
      __syncthreads();
      cur ^= 1;
    }
  }

  const float* bias = (m == 0) ? bq : (m == 1) ? bk : bv;
  u16* qk = (m == 0) ? qb : kb;
#pragma unroll
  for (int mr = 0; mr < 2; ++mr) {
#pragma unroll
    for (int nr = 0; nr < 4; ++nr) {
      int col = wc * 64 + nr * 16 + (lane & 15);
      float bc = bias[col];
      int grow = row0 + wr * 32 + mr * 16 + (lane >> 4) * 4;
      if (m == 2) {
        // permuted V^T store: within each 32-s block, s' = g*8 + mr*4 + rr
        int bb = grow >> 11;
        int sbase = ((grow & 2047) & ~31) | ((lane >> 4) * 8 + mr * 4);
        ushort4 u;
        u.x = bfbits(acc[mr][nr][0] + bc);
        u.y = bfbits(acc[mr][nr][1] + bc);
        u.z = bfbits(acc[mr][nr][2] + bc);
        u.w = bfbits(acc[mr][nr][3] + bc);
        *(ushort4*)&vt[(size_t)bb * 262144 + (size_t)col * 2048 + sbase] = u;
      } else {
#pragma unroll
        for (int r = 0; r < 4; ++r)
          qk[(size_t)(grow + r) * 128 + col] = bfbits(acc[mr][nr][r] + bc);
      }
    }
  }
}

// ---------------- Flash attention: 32q/wave, 8-way KV split ------------------
// Each wave owns 32 q-rows (two 16-q groups A,B) -> every K/V b128 fragment
// read feeds 2 MFMAs (LDS reads per FLOP halved vs R5).
// PV A-fragment = single b128 from column-permuted vt. P stays in-register.
// LDS 32 KB single-buffered; grid (16,8,4)=512 blocks, 2/CU.
__global__ __launch_bounds__(256, 2) void attn_kernel(
    const u16* __restrict__ qb, const u16* __restrict__ kb, const u16* __restrict__ vt,
    float* __restrict__ Opart, float* __restrict__ Mws, float* __restrict__ Lws)
{
  __shared__ __attribute__((aligned(16))) u16 sk[64 * 128];
  __shared__ __attribute__((aligned(16))) u16 sv[128 * 64];
  const int tid = threadIdx.x, wid = tid >> 6, lane = tid & 63;
  const int g = lane >> 4, q16 = lane & 15;
  const int qt = blockIdx.x, split = blockIdx.y, b = blockIdx.z;
  const size_t qgA = (size_t)b * 2048 + qt * 128 + wid * 32;   // group B = +16
  const u16* kbase = kb + ((size_t)b * 2048 + split * 256) * 128;
  const u16* vbase = vt + (size_t)b * 262144 + split * 256;
  const float scale = 0.08838834764831845f;   // 128^-0.5

  bf16x8 qfA[4], qfB[4];
#pragma unroll
  for (int kg = 0; kg < 4; ++kg) {
    qfA[kg] = *(const bf16x8*)&qb[(qgA + q16) * 128 + kg * 32 + g * 8];
    qfB[kg] = *(const bf16x8*)&qb[(qgA + 16 + q16) * 128 + kg * 32 + g * 8];
  }

  float mA = -INFINITY, lA = 0.f, mB = -INFINITY, lB = 0.f;
  f32x4 accA[8] = {}, accB[8] = {};

  for (int t = 0; t < 4; ++t) {
#pragma unroll
    for (int i = 0; i < 4; ++i) {  // K-tile: 64 rows x 16 chunks of 16B
      int fc = i * 256 + tid; int r = fc >> 4, c = fc & 15;
      gl_lds16(kbase + (size_t)(t * 64 + r) * 128 + ((c ^ (r & 7)) << 3),
               (char*)sk + fc * 16);
    }
#pragma unroll
    for (int i = 0; i < 4; ++i) {  // V^T-tile: 128 rows x 8 chunks of 16B
      int fc = i * 256 + tid; int r = fc >> 3, c = fc & 7;
      gl_lds16(vbase + (size_t)r * 2048 + t * 64 + ((c ^ (r & 7)) << 3),
               (char*)sv + fc * 16);
    }
    asm volatile("s_waitcnt vmcnt(0)" ::: "memory");
    __syncthreads();

    // S^T for both q-groups; each kf read feeds 2 MFMAs
    f32x4 sTa[4] = {}, sTb[4] = {};
#pragma unroll
    for (int kg = 0; kg < 4; ++kg)
#pragma unroll
      for (int jg = 0; jg < 4; ++jg) {
        int row = jg * 16 + q16;
        int ch = (kg * 4 + g) ^ (row & 7);
        bf16x8 kf = *(const bf16x8*)(sk + row * 128 + ch * 8);
        sTa[jg] = __builtin_amdgcn_mfma_f32_16x16x32_bf16(kf, qfA[kg], sTa[jg], 0, 0, 0);
        sTb[jg] = __builtin_amdgcn_mfma_f32_16x16x32_bf16(kf, qfB[kg], sTb[jg], 0, 0, 0);
      }

    // ---- softmax group A (lane-local 16 values + 2 shfl) ----
    u32 WpA[4][2], WpB[4][2];
    {
      float mx = fmaxf(fmaxf(fmaxf(sTa[0][0], sTa[0][1]), fmaxf(sTa[0][2], sTa[0][3])),
                       fmaxf(fmaxf(sTa[1][0], sTa[1][1]), fmaxf(sTa[1][2], sTa[1][3])));
      mx = fmaxf(mx, fmaxf(fmaxf(fmaxf(sTa[2][0], sTa[2][1]), fmaxf(sTa[2][2], sTa[2][3])),
                           fmaxf(fmaxf(sTa[3][0], sTa[3][1]), fmaxf(sTa[3][2], sTa[3][3]))));
      mx = fmaxf(mx, __shfl_xor(mx, 16));
      mx = fmaxf(mx, __shfl_xor(mx, 32));
      float mn = fmaxf(mA, mx * scale);
      float rs = 0.f;
#pragma unroll
      for (int jg = 0; jg < 4; ++jg) {
        float e0 = __expf(fmaf(sTa[jg][0], scale, -mn));
        float e1 = __expf(fmaf(sTa[jg][1], scale, -mn));
        float e2 = __expf(fmaf(sTa[jg][2], scale, -mn));
        float e3 = __expf(fmaf(sTa[jg][3], scale, -mn));
        rs += (e0 + e1) + (e2 + e3);
        WpA[jg][0] = pk2(e0, e1);
        WpA[jg][1] = pk2(e2, e3);
      }
      rs += __shfl_xor(rs, 16);
      rs += __shfl_xor(rs, 32);
      float aa = __expf(mA - mn);
      lA = lA * aa + rs; mA = mn;
#pragma unroll
      for (int dg = 0; dg < 8; ++dg) accA[dg] *= aa;
    }
    // ---- softmax group B ----
    {
      float mx = fmaxf(fmaxf(fmaxf(sTb[0][0], sTb[0][1]), fmaxf(sTb[0][2], sTb[0][3])),
                       fmaxf(fmaxf(sTb[1][0], sTb[1][1]), fmaxf(sTb[1][2], sTb[1][3])));
      mx = fmaxf(mx, fmaxf(fmaxf(fmaxf(sTb[2][0], sTb[2][1]), fmaxf(sTb[2][2], sTb[2][3])),
                           fmaxf(fmaxf(sTb[3][0], sTb[3][1]), fmaxf(sTb[3][2], sTb[3][3]))));
      mx = fmaxf(mx, __shfl_xor(mx, 16));
      mx = fmaxf(mx, __shfl_xor(mx, 32));
      float mn = fmaxf(mB, mx * scale);
      float rs = 0.f;
#pragma unroll
      for (int jg = 0; jg < 4; ++jg) {
        float e0 = __expf(fmaf(sTb[jg][0], scale, -mn));
        float e1 = __expf(fmaf(sTb[jg][1], scale, -mn));
        float e2 = __expf(fmaf(sTb[jg][2], scale, -mn));
        float e3 = __expf(fmaf(sTb[jg][3], scale, -mn));
        rs += (e0 + e1) + (e2 + e3);
        WpB[jg][0] = pk2(e0, e1);
        WpB[jg][1] = pk2(e2, e3);
      }
      rs += __shfl_xor(rs, 16);
      rs += __shfl_xor(rs, 32);
      float aa = __expf(mB - mn);
      lB = lB * aa + rs; mB = mn;
#pragma unroll
      for (int dg = 0; dg < 8; ++dg) accB[dg] *= aa;
    }

    bf16x8 pA[2], pB[2];
#pragma unroll
    for (int k2 = 0; k2 < 2; ++k2) {
      u32x4 wa = {WpA[2 * k2][0], WpA[2 * k2][1], WpA[2 * k2 + 1][0], WpA[2 * k2 + 1][1]};
      u32x4 wb = {WpB[2 * k2][0], WpB[2 * k2][1], WpB[2 * k2 + 1][0], WpB[2 * k2 + 1][1]};
      pA[k2] = __builtin_bit_cast(bf16x8, wa);
      pB[k2] = __builtin_bit_cast(bf16x8, wb);
    }

    // PV: one b128 V-fragment per (dg,k2), feeds 2 MFMAs
#pragma unroll
    for (int dg = 0; dg < 8; ++dg) {
      int row = dg * 16 + q16;
#pragma unroll
      for (int k2 = 0; k2 < 2; ++k2) {
        int ch = (4 * k2 + g) ^ (row & 7);
        bf16x8 vf = *(const bf16x8*)(sv + row * 64 + ch * 8);
        accA[dg] = __builtin_amdgcn_mfma_f32_16x16x32_bf16(vf, pA[k2], accA[dg], 0, 0, 0);
        accB[dg] = __builtin_amdgcn_mfma_f32_16x16x32_bf16(vf, pB[k2], accB[dg], 0, 0, 0);
      }
    }
    __syncthreads();   // tiles consumed; safe to restage next iter
  }

  const size_t prow = (size_t)split * 8192 + qgA;
#pragma unroll
  for (int dg = 0; dg < 8; ++dg) {
    *(f32x4*)&Opart[(prow + q16) * 128 + dg * 16 + g * 4] = accA[dg];
    *(f32x4*)&Opart[(prow + 16 + q16) * 128 + dg * 16 + g * 4] = accB[dg];
  }
  if (lane < 16) {
    Mws[prow + lane] = mA; Lws[prow + lane] = lA;
    Mws[prow + 16 + lane] = mB; Lws[prow + 16 + lane] = lB;
  }
}

// ---------------- combine the 8 KV-split partials ---------------------------
__global__ __launch_bounds__(256) void combine_kernel(
    const float* __restrict__ Opart, const float* __restrict__ Mws,
    const float* __restrict__ Lws, float* __restrict__ out)
{
  int idx4 = blockIdx.x * 256 + threadIdx.x;   // 0..262143 (f32x4 units)
  int row = idx4 >> 5;
  float m[8], l[8];
#pragma unroll
  for (int s = 0; s < 8; ++s) {
    m[s] = Mws[s * 8192 + row];
    l[s] = Lws[s * 8192 + row];
  }
  float ms = m[0];
#pragma unroll
  for (int s = 1; s < 8; ++s) ms = fmaxf(ms, m[s]);
  float den = 0.f, w[8];
#pragma unroll
  for (int s = 0; s < 8; ++s) { w[s] = __expf(m[s] - ms); den += w[s] * l[s]; }
  float inv = 1.0f / den;
  f32x4 acc = {0.f, 0.f, 0.f, 0.f};
#pragma unroll
  for (int s = 0; s < 8; ++s)
    acc += w[s] * *(const f32x4*)&Opart[(size_t)s * 1048576 + (size_t)idx4 * 4];
  *(f32x4*)&out[(size_t)idx4 * 4] = acc * inv;
}

// ---------------- launch ----------------------------------------------------
// Workspace (~39.5 MB; d_ws is 256 MB per the harness poison fills):
//   0      : qb   (2 MB)      2 MB : kb (2 MB)     4 MB : vt (2 MB, col-perm)
//   6 MB   : Wt   (0.75 MB)   7 MB : Opart ([8][8192][128] f32, 32 MB)
//   39 MB  : Mws  (256 KB)    39.25 MB : Lws (256 KB)
extern "C" void kernel_launch(void* const* d_in, const int* in_sizes, int n_in,
                              void* d_out, int out_size, void* d_ws, size_t ws_size,
                              hipStream_t stream)
{
  (void)in_sizes; (void)n_in; (void)out_size; (void)ws_size;
  const float* x  = (const float*)d_in[0];
  const float* Wq = (const float*)d_in[1];
  const float* bq = (const float*)d_in[2];
  const float* Wk = (const float*)d_in[3];
  const float* bk = (const float*)d_in[4];
  const float* Wv = (const float*)d_in[5];
  const float* bv = (const float*)d_in[6];
  char* ws = (char*)d_ws;
  u16* qbuf   = (u16*)(ws);
  u16* kbuf   = (u16*)(ws + (2u << 20));
  u16* vtbuf  = (u16*)(ws + (4u << 20));
  u16* Wt     = (u16*)(ws + (6u << 20));
  float* Opart = (float*)(ws + (7u << 20));
  float* Mws   = (float*)(ws + (39u << 20));
  float* Lws   = (float*)(ws + (39u << 20) + (256u << 10));

  wprep_kernel<<<96, 256, 0, stream>>>(Wq, Wk, Wv, Wt);
  qkv_gemm<<<dim3(128, 3), 256, 0, stream>>>(x, Wt, bq, bk, bv, qbuf, kbuf, vtbuf);
  attn_kernel<<<dim3(16, 8, 4), 256, 0, stream>>>(qbuf, kbuf, vtbuf, Opart, Mws, Lws);
  combine_kernel<<<1024, 256, 0, stream>>>(Opart, Mws, Lws, (float*)d_out);
}

// Round 8
// 61.053 us; speedup vs baseline: 2.3876x; 1.0107x over previous
//
#include <hip/hip_runtime.h>

typedef unsigned short u16;
typedef unsigned int u32;
typedef __bf16 bf16;
typedef __bf16 bf16x8 __attribute__((ext_vector_type(8)));
typedef float f32x4 __attribute__((ext_vector_type(4)));
typedef u32 u32x4 __attribute__((ext_vector_type(4)));

// Problem constants: B=4, S=2048, DIM=1024, DK=DV=128, rows = B*S = 8192.

__device__ __forceinline__ void gl_lds16(const void* g, void* l) {
  __builtin_amdgcn_global_load_lds(
      (const __attribute__((address_space(1))) void*)g,
      (__attribute__((address_space(3))) void*)l, 16, 0, 0);
}
__device__ __forceinline__ u16 bfbits(float f) {
  return __builtin_bit_cast(u16, (bf16)f);
}
__device__ __forceinline__ u32 pk2(float lo, float hi) {
  return (u32)bfbits(lo) | ((u32)bfbits(hi) << 16);
}

// ---------------- W transpose + convert: Wt[m][n][k] = bf16(W_m[k][n]) -------
__global__ __launch_bounds__(256) void wprep_kernel(
    const float* __restrict__ Wq, const float* __restrict__ Wk,
    const float* __restrict__ Wv, u16* __restrict__ Wt) {
  __shared__ u16 st[64][72];
  const int tid = threadIdx.x;
  const int m = blockIdx.x >> 5, rem = blockIdx.x & 31, kt = rem >> 1, nt = rem & 1;
  const float* W = (m == 0) ? Wq : (m == 1) ? Wk : Wv;
  const int k0 = kt * 64, n0 = nt * 64;
#pragma unroll
  for (int i = 0; i < 4; ++i) {
    int kk = i * 16 + (tid >> 4), nn = (tid & 15) * 4;
    f32x4 w = *(const f32x4*)&W[(size_t)(k0 + kk) * 128 + n0 + nn];
    st[kk][nn]     = bfbits(w[0]); st[kk][nn + 1] = bfbits(w[1]);
    st[kk][nn + 2] = bfbits(w[2]); st[kk][nn + 3] = bfbits(w[3]);
  }
  __syncthreads();
#pragma unroll
  for (int i = 0; i < 4; ++i) {
    int nn = i * 16 + (tid >> 4), kk = (tid & 15) * 4;
    ushort4 u;
    u.x = st[kk][nn]; u.y = st[kk + 1][nn]; u.z = st[kk + 2][nn]; u.w = st[kk + 3][nn];
    *(ushort4*)&Wt[(size_t)m * 131072 + (size_t)(n0 + nn) * 1024 + k0 + kk] = u;
  }
}

// ---------------- QKV projection GEMM (unchanged from R7) --------------------
// V store permutes columns within each 32-s block: s' = (s&~31)|(g*8+mr*4+rr)
// so attn's PV A-fragment is a single contiguous b128.
__global__ __launch_bounds__(256) void qkv_gemm(
    const float* __restrict__ x, const u16* __restrict__ Wt,
    const float* __restrict__ bq, const float* __restrict__ bk, const float* __restrict__ bv,
    u16* __restrict__ qb, u16* __restrict__ kb, u16* __restrict__ vt)
{
  __shared__ __attribute__((aligned(16))) float sx[2][64 * 64];
  __shared__ __attribute__((aligned(16))) u16   sw[2][128 * 64];
  const int tid = threadIdx.x, wid = tid >> 6, lane = tid & 63;
  const int m = blockIdx.y;
  const int row0 = blockIdx.x * 64;
  const u16* W = Wt + (size_t)m * 131072;
  const int wr = wid >> 1, wc = wid & 1;

  auto STAGE = [&](int buf, int k0) {
#pragma unroll
    for (int i = 0; i < 4; ++i) {
      int fc = i * 256 + tid; int r = fc >> 4, c = fc & 15;
      gl_lds16(x + (size_t)(row0 + r) * 1024 + k0 + ((c ^ (r & 15)) << 2),
               (char*)&sx[buf][0] + fc * 16);
    }
#pragma unroll
    for (int i = 0; i < 4; ++i) {
      int fc = i * 256 + tid; int r = fc >> 3, c = fc & 7;
      gl_lds16(W + (size_t)r * 1024 + k0 + ((c ^ (r & 7)) << 3),
               (char*)&sw[buf][0] + fc * 16);
    }
  };

  f32x4 acc[2][4] = {};
  STAGE(0, 0);
  asm volatile("s_waitcnt vmcnt(0)" ::: "memory");
  __syncthreads();
  int cur = 0;

  for (int kt = 0; kt < 16; ++kt) {
    if (kt < 15) STAGE(cur ^ 1, (kt + 1) * 64);
    const float* sxc = &sx[cur][0];
    const u16*   swc = &sw[cur][0];
#pragma unroll
    for (int ks = 0; ks < 2; ++ks) {
      bf16x8 af[2], bfr[4];
#pragma unroll
      for (int mr = 0; mr < 2; ++mr) {
        int row = wr * 32 + mr * 16 + (lane & 15);
        int c0 = ks * 8 + (lane >> 4) * 2;
        f32x4 lo = *(const f32x4*)(sxc + row * 64 + ((c0 ^ (row & 15)) << 2));
        f32x4 hi = *(const f32x4*)(sxc + row * 64 + (((c0 + 1) ^ (row & 15)) << 2));
        bf16x8 v;
        v[0] = (bf16)lo[0]; v[1] = (bf16)lo[1]; v[2] = (bf16)lo[2]; v[3] = (bf16)lo[3];
        v[4] = (bf16)hi[0]; v[5] = (bf16)hi[1]; v[6] = (bf16)hi[2]; v[7] = (bf16)hi[3];
        af[mr] = v;
      }
#pragma unroll
      for (int nr = 0; nr < 4; ++nr) {
        int row = wc * 64 + nr * 16 + (lane & 15);
        int ch = (ks * 4 + (lane >> 4)) ^ (row & 7);
        bfr[nr] = *(const bf16x8*)(swc + row * 64 + ch * 8);
      }
#pragma unroll
      for (int mr = 0; mr < 2; ++mr)
#pragma unroll
        for (int nr = 0; nr < 4; ++nr)
          acc[mr][nr] = __builtin_amdgcn_mfma_f32_16x16x32_bf16(af[mr], bfr[nr], acc[mr][nr], 0, 0, 0);
    }
    if (kt < 15) {
      asm volatile("s_waitcnt vmcnt(0)" ::: "memory");
      __syncthreads();
      cur ^= 1;
    }
  }

  const float* bias = (m == 0) ? bq : (m == 1) ? bk : bv;
  u16* qk = (m == 0) ? qb : kb;
#pragma unroll
  for (int mr = 0; mr < 2; ++mr) {
#pragma unroll
    for (int nr = 0; nr < 4; ++nr) {
      int col = wc * 64 + nr * 16 + (lane & 15);
      float bc = bias[col];
      int grow = row0 + wr * 32 + mr * 16 + (lane >> 4) * 4;
      if (m == 2) {
        int bb = grow >> 11;
        int sbase = ((grow & 2047) & ~31) | ((lane >> 4) * 8 + mr * 4);
        ushort4 u;
        u.x = bfbits(acc[mr][nr][0] + bc);
        u.y = bfbits(acc[mr][nr][1] + bc);
        u.z = bfbits(acc[mr][nr][2] + bc);
        u.w = bfbits(acc[mr][nr][3] + bc);
        *(ushort4*)&vt[(size_t)bb * 262144 + (size_t)col * 2048 + sbase] = u;
      } else {
#pragma unroll
        for (int r = 0; r < 4; ++r)
          qk[(size_t)(grow + r) * 128 + col] = bfbits(acc[mr][nr][r] + bc);
      }
    }
  }
}

// ---------------- Split-free flash attention + in-block combine --------------
// grid (64 qt, 4 b) = 256 blocks = 1/CU.  Block tile: 32 q-rows.
// Each wave owns a KV-quarter (512 rows) with wave-PRIVATE LDS staging:
// no __syncthreads in the KV loop; counted-vmcnt prefetch hides K/V latency.
// Per-wave 32 q = two 16-q groups (A,B) sharing every K/V fragment read.
// After the loop: one barrier, partials (O,m,l) merge via LDS, write d_out.
union ALDS {
  u16 stg[4][16384];                 // per-wave: [0..8191] K, [8192..16383] V
  struct {
    float oc[4][32 * 132];           // per-wave unnormalized O partial
    float ml[4][2][32];              // m,l per wave per q-row
    float wfin[4][32];               // final combine weights
  } cb;
};

__global__ __launch_bounds__(256) void attn_kernel(
    const u16* __restrict__ qb, const u16* __restrict__ kb, const u16* __restrict__ vt,
    float* __restrict__ out)
{
  __shared__ __attribute__((aligned(16))) ALDS lds;
  const int tid = threadIdx.x, wid = tid >> 6, lane = tid & 63;
  const int g = lane >> 4, q16 = lane & 15;
  const int qt = blockIdx.x, b = blockIdx.y;
  const size_t qgA = (size_t)b * 2048 + qt * 32;   // rows qgA..qgA+31
  const u16* kbw = kb + ((size_t)b * 2048 + wid * 512) * 128;
  const u16* vbw = vt + (size_t)b * 262144 + wid * 512;
  u16* skw = &lds.stg[wid][0];
  u16* svw = &lds.stg[wid][8192];
  const float scale = 0.08838834764831845f;   // 128^-0.5

  // Q fragments first (oldest vm ops, drained by the first counted wait).
  bf16x8 qfA[4], qfB[4];
#pragma unroll
  for (int kg = 0; kg < 4; ++kg) {
    qfA[kg] = *(const bf16x8*)&qb[(qgA + q16) * 128 + kg * 32 + g * 8];
    qfB[kg] = *(const bf16x8*)&qb[(qgA + 16 + q16) * 128 + kg * 32 + g * 8];
  }

  auto SK = [&](int t) {   // K-tile 64x128 bf16: 16 chunks/lane
#pragma unroll
    for (int i = 0; i < 16; ++i) {
      int fc = i * 64 + lane; int r = fc >> 4, c = fc & 15;
      gl_lds16(kbw + (size_t)(t * 64 + r) * 128 + ((c ^ (r & 7)) << 3),
               (char*)skw + fc * 16);
    }
  };
  auto SV = [&](int t) {   // V^T-tile 128x64 bf16: 16 chunks/lane
#pragma unroll
    for (int i = 0; i < 16; ++i) {
      int fc = i * 64 + lane; int r = fc >> 3, c = fc & 7;
      gl_lds16(vbw + (size_t)r * 2048 + t * 64 + ((c ^ (r & 7)) << 3),
               (char*)svw + fc * 16);
    }
  };

  float mA = -INFINITY, lA = 0.f, mB = -INFINITY, lB = 0.f;
  f32x4 accA[8] = {}, accB[8] = {};

  SK(0); SV(0);
  for (int t = 0; t < 8; ++t) {
    // K(t) ready (16 oldest of the 32 outstanding)
    asm volatile("s_waitcnt vmcnt(16)" ::: "memory");

    f32x4 sTa[4] = {}, sTb[4] = {};
#pragma unroll
    for (int kg = 0; kg < 4; ++kg)
#pragma unroll
      for (int jg = 0; jg < 4; ++jg) {
        int row = jg * 16 + q16;
        int ch = (kg * 4 + g) ^ (row & 7);
        bf16x8 kf = *(const bf16x8*)(skw + row * 128 + ch * 8);
        sTa[jg] = __builtin_amdgcn_mfma_f32_16x16x32_bf16(kf, qfA[kg], sTa[jg], 0, 0, 0);
        sTb[jg] = __builtin_amdgcn_mfma_f32_16x16x32_bf16(kf, qfB[kg], sTb[jg], 0, 0, 0);
      }
    __builtin_amdgcn_sched_barrier(0);
    if (t < 7) SK(t + 1);              // K LDS free: frag ds_reads retired

    // ---- softmax A ----
    u32 WpA[4][2], WpB[4][2];
    {
      float mx = fmaxf(fmaxf(fmaxf(sTa[0][0], sTa[0][1]), fmaxf(sTa[0][2], sTa[0][3])),
                       fmaxf(fmaxf(sTa[1][0], sTa[1][1]), fmaxf(sTa[1][2], sTa[1][3])));
      mx = fmaxf(mx, fmaxf(fmaxf(fmaxf(sTa[2][0], sTa[2][1]), fmaxf(sTa[2][2], sTa[2][3])),
                           fmaxf(fmaxf(sTa[3][0], sTa[3][1]), fmaxf(sTa[3][2], sTa[3][3]))));
      mx = fmaxf(mx, __shfl_xor(mx, 16));
      mx = fmaxf(mx, __shfl_xor(mx, 32));
      float mn = fmaxf(mA, mx * scale);
      float rs = 0.f;
#pragma unroll
      for (int jg = 0; jg < 4; ++jg) {
        float e0 = __expf(fmaf(sTa[jg][0], scale, -mn));
        float e1 = __expf(fmaf(sTa[jg][1], scale, -mn));
        float e2 = __expf(fmaf(sTa[jg][2], scale, -mn));
        float e3 = __expf(fmaf(sTa[jg][3], scale, -mn));
        rs += (e0 + e1) + (e2 + e3);
        WpA[jg][0] = pk2(e0, e1);
        WpA[jg][1] = pk2(e2, e3);
      }
      rs += __shfl_xor(rs, 16);
      rs += __shfl_xor(rs, 32);
      float aa = __expf(mA - mn);
      lA = lA * aa + rs; mA = mn;
#pragma unroll
      for (int dg = 0; dg < 8; ++dg) accA[dg] *= aa;
    }
    // ---- softmax B ----
    {
      float mx = fmaxf(fmaxf(fmaxf(sTb[0][0], sTb[0][1]), fmaxf(sTb[0][2], sTb[0][3])),
                       fmaxf(fmaxf(sTb[1][0], sTb[1][1]), fmaxf(sTb[1][2], sTb[1][3])));
      mx = fmaxf(mx, fmaxf(fmaxf(fmaxf(sTb[2][0], sTb[2][1]), fmaxf(sTb[2][2], sTb[2][3])),
                           fmaxf(fmaxf(sTb[3][0], sTb[3][1]), fmaxf(sTb[3][2], sTb[3][3]))));
      mx = fmaxf(mx, __shfl_xor(mx, 16));
      mx = fmaxf(mx, __shfl_xor(mx, 32));
      float mn = fmaxf(mB, mx * scale);
      float rs = 0.f;
#pragma unroll
      for (int jg = 0; jg < 4; ++jg) {
        float e0 = __expf(fmaf(sTb[jg][0], scale, -mn));
        float e1 = __expf(fmaf(sTb[jg][1], scale, -mn));
        float e2 = __expf(fmaf(sTb[jg][2], scale, -mn));
        float e3 = __expf(fmaf(sTb[jg][3], scale, -mn));
        rs += (e0 + e1) + (e2 + e3);
        WpB[jg][0] = pk2(e0, e1);
        WpB[jg][1] = pk2(e2, e3);
      }
      rs += __shfl_xor(rs, 16);
      rs += __shfl_xor(rs, 32);
      float aa = __expf(mB - mn);
      lB = lB * aa + rs; mB = mn;
#pragma unroll
      for (int dg = 0; dg < 8; ++dg) accB[dg] *= aa;
    }

    bf16x8 pA[2], pB[2];
#pragma unroll
    for (int k2 = 0; k2 < 2; ++k2) {
      u32x4 wa = {WpA[2 * k2][0], WpA[2 * k2][1], WpA[2 * k2 + 1][0], WpA[2 * k2 + 1][1]};
      u32x4 wb = {WpB[2 * k2][0], WpB[2 * k2][1], WpB[2 * k2 + 1][0], WpB[2 * k2 + 1][1]};
      pA[k2] = __builtin_bit_cast(bf16x8, wa);
      pB[k2] = __builtin_bit_cast(bf16x8, wb);
    }

    // V(t) ready (K(t+1) may stay in flight)
    if (t < 7) { asm volatile("s_waitcnt vmcnt(16)" ::: "memory"); }
    else       { asm volatile("s_waitcnt vmcnt(0)"  ::: "memory"); }

#pragma unroll
    for (int dg = 0; dg < 8; ++dg) {
      int row = dg * 16 + q16;
#pragma unroll
      for (int k2 = 0; k2 < 2; ++k2) {
        int ch = (4 * k2 + g) ^ (row & 7);
        bf16x8 vf = *(const bf16x8*)(svw + row * 64 + ch * 8);
        accA[dg] = __builtin_amdgcn_mfma_f32_16x16x32_bf16(vf, pA[k2], accA[dg], 0, 0, 0);
        accB[dg] = __builtin_amdgcn_mfma_f32_16x16x32_bf16(vf, pB[k2], accB[dg], 0, 0, 0);
      }
    }
    __builtin_amdgcn_sched_barrier(0);
    if (t < 7) SV(t + 1);              // V LDS free: frag ds_reads retired
  }

  // ---- in-block combine of the 4 wave partials ----
  __syncthreads();                     // all staging consumed; reuse LDS
  {
    float* ocp = &lds.cb.oc[wid][0];
#pragma unroll
    for (int dg = 0; dg < 8; ++dg) {
      *(f32x4*)&ocp[q16 * 132 + dg * 16 + g * 4] = accA[dg];
      *(f32x4*)&ocp[(16 + q16) * 132 + dg * 16 + g * 4] = accB[dg];
    }
    if (g == 0) {
      lds.cb.ml[wid][0][q16] = mA; lds.cb.ml[wid][1][q16] = lA;
      lds.cb.ml[wid][0][16 + q16] = mB; lds.cb.ml[wid][1][16 + q16] = lB;
    }
  }
  __syncthreads();
  if (tid < 32) {
    int q = tid;
    float m0 = lds.cb.ml[0][0][q], m1 = lds.cb.ml[1][0][q];
    float m2 = lds.cb.ml[2][0][q], m3 = lds.cb.ml[3][0][q];
    float ms = fmaxf(fmaxf(m0, m1), fmaxf(m2, m3));
    float w0 = __expf(m0 - ms), w1 = __expf(m1 - ms);
    float w2 = __expf(m2 - ms), w3 = __expf(m3 - ms);
    float den = w0 * lds.cb.ml[0][1][q] + w1 * lds.cb.ml[1][1][q]
              + w2 * lds.cb.ml[2][1][q] + w3 * lds.cb.ml[3][1][q];
    float inv = 1.0f / den;
    lds.cb.wfin[0][q] = w0 * inv; lds.cb.wfin[1][q] = w1 * inv;
    lds.cb.wfin[2][q] = w2 * inv; lds.cb.wfin[3][q] = w3 * inv;
  }
  __syncthreads();
#pragma unroll
  for (int h = 0; h < 4; ++h) {
    int idx = h * 256 + tid;           // 1024 f32x4 work items: 32 q x 32 d4
    int q = idx >> 5, d4 = idx & 31;
    f32x4 v = lds.cb.wfin[0][q] * *(const f32x4*)&lds.cb.oc[0][q * 132 + d4 * 4]
            + lds.cb.wfin[1][q] * *(const f32x4*)&lds.cb.oc[1][q * 132 + d4 * 4]
            + lds.cb.wfin[2][q] * *(const f32x4*)&lds.cb.oc[2][q * 132 + d4 * 4]
            + lds.cb.wfin[3][q] * *(const f32x4*)&lds.cb.oc[3][q * 132 + d4 * 4];
    *(f32x4*)&out[((size_t)b * 2048 + qt * 32 + q) * 128 + d4 * 4] = v;
  }
}

// ---------------- launch ----------------------------------------------------
// Workspace: 0 qb (2MB) | 2MB kb (2MB) | 4MB vt (2MB, col-perm) | 6MB Wt (0.75MB)
extern "C" void kernel_launch(void* const* d_in, const int* in_sizes, int n_in,
                              void* d_out, int out_size, void* d_ws, size_t ws_size,
                              hipStream_t stream)
{
  (void)in_sizes; (void)n_in; (void)out_size; (void)ws_size;
  const float* x  = (const float*)d_in[0];
  const float* Wq = (const float*)d_in[1];
  const float* bq = (const float*)d_in[2];
  const float* Wk = (const float*)d_in[3];
  const float* bk = (const float*)d_in[4];
  const float* Wv = (const float*)d_in[5];
  const float* bv = (const float*)d_in[6];
  char* ws = (char*)d_ws;
  u16* qbuf  = (u16*)(ws);
  u16* kbuf  = (u16*)(ws + (2u << 20));
  u16* vtbuf = (u16*)(ws + (4u << 20));
  u16* Wt    = (u16*)(ws + (6u << 20));

  wprep_kernel<<<96, 256, 0, stream>>>(Wq, Wk, Wv, Wt);
  qkv_gemm<<<dim3(128, 3), 256, 0, stream>>>(x, Wt, bq, bk, bv, qbuf, kbuf, vtbuf);
  attn_kernel<<<dim3(64, 4), 256, 0, stream>>>(qbuf, kbuf, vtbuf, (float*)d_out);
}